// Round 1
// baseline (4672.153 us; speedup 1.0000x reference)
//
#include <hip/hip_runtime.h>
#include <hip/hip_bf16.h>

// StyleBlock: B=16, C_IN=512, C_OUT=512, D_LATENT=512, H=W=64, K=3
// Algebra: fold style into x (LDS staging), fold conv_coef*sigma_inv into epilogue.
// => standard shared-weight 3x3 conv; never materialize per-sample weights.

#define B_    16
#define CIN   512
#define COUT  512
#define DLAT  512
#define H_    64
#define W_    64

constexpr float LIN_COEF  = 0.04419417382415922f;   // 1/sqrt(512)
constexpr float CONV_COEF = 0.014731391274719739f;  // 1/sqrt(512*9)

// ---------------- style[b,c] = style_b[c] + lin_coef * <w[b,:], style_w[c,:]> ----
__global__ __launch_bounds__(256) void style_kernel(
    const float* __restrict__ w, const float* __restrict__ style_w,
    const float* __restrict__ style_b, float* __restrict__ style) {
  int gw   = blockIdx.x * 4 + (threadIdx.x >> 6);  // one wave per (b,c)
  int lane = threadIdx.x & 63;
  int b = gw >> 9, c = gw & 511;
  const float* wp = w + b * DLAT;
  const float* sw = style_w + c * DLAT;
  float v = 0.f;
  for (int d = lane; d < DLAT; d += 64) v = fmaf(wp[d], sw[d], v);
  #pragma unroll
  for (int off = 32; off > 0; off >>= 1) v += __shfl_down(v, off, 64);
  if (lane == 0) style[b * CIN + c] = fmaf(v, LIN_COEF, style_b[c]);
}

// ---------------- wsq[o,i] = sum_k conv_w[o,i,k]^2 --------------------------------
__global__ __launch_bounds__(256) void wsq_kernel(
    const float* __restrict__ conv_w, float* __restrict__ wsq) {
  int idx = blockIdx.x * 256 + threadIdx.x;   // idx = o*512 + i
  const float* p = conv_w + (size_t)idx * 9;
  float s = 0.f;
  #pragma unroll
  for (int t = 0; t < 9; ++t) s = fmaf(p[t], p[t], s);
  wsq[idx] = s;
}

// ---- scale_bo[b,o] = conv_coef * rsqrt(conv_coef^2 * sum_i style^2*wsq + eps) ----
__global__ __launch_bounds__(256) void scale_kernel(
    const float* __restrict__ style, const float* __restrict__ wsq,
    float* __restrict__ scale_bo) {
  int gw   = blockIdx.x * 4 + (threadIdx.x >> 6);  // one wave per (b,o)
  int lane = threadIdx.x & 63;
  int b = gw >> 9, o = gw & 511;
  const float* st = style + b * CIN;
  const float* wq = wsq + o * CIN;
  float v = 0.f;
  for (int i = lane; i < CIN; i += 64) { float s = st[i]; v = fmaf(s * s, wq[i], v); }
  #pragma unroll
  for (int off = 32; off > 0; off >>= 1) v += __shfl_down(v, off, 64);
  if (lane == 0)
    scale_bo[b * COUT + o] = CONV_COEF * rsqrtf(fmaf(CONV_COEF * CONV_COEF, v, 1e-8f));
}

// ---------------- main conv: block = 32 ochan x (8 rows x 64 cols) ----------------
#define OTILE   32
#define HTILE   8
#define ICCH    8
#define XSTR    67          // 66 cols + 1 pad; 67 % 32 == 3 -> worst 2-way LDS aliasing (free)
#define XROWS   10          // 8 output rows + 2 halo

__global__ __launch_bounds__(256) void conv_kernel(
    const float* __restrict__ x, const float* __restrict__ style,
    const float* __restrict__ conv_w, const float* __restrict__ scale_bo,
    const float* __restrict__ noise, const float* __restrict__ scale_noise,
    const float* __restrict__ bias, float* __restrict__ out) {
  __shared__ float xt[ICCH * XROWS * XSTR];   // 5360 f = 21.4 KB
  __shared__ float wt[OTILE * 72];            // 2304 f =  9.2 KB

  const int tid = threadIdx.x;
  const int b  = blockIdx.z;
  const int o0 = blockIdx.y * OTILE;
  const int h0 = blockIdx.x * HTILE;
  const int lane = tid & 63, oq = tid >> 6;   // oq: which group of 8 ochans
  const int r  = lane >> 3;                   // output row within tile (0..7)
  const int cg = lane & 7;                    // column group (8 cols each)

  float acc[8][8];
  #pragma unroll
  for (int a = 0; a < 8; ++a)
    #pragma unroll
    for (int c = 0; c < 8; ++c) acc[a][c] = 0.f;

  for (int ic0 = 0; ic0 < CIN; ic0 += ICCH) {
    // ---- stage x chunk (style folded in, zero-padded halo) ----
    for (int j = tid; j < ICCH * XROWS * XSTR; j += 256) {
      int i   = j / (XROWS * XSTR);
      int rem = j - i * (XROWS * XSTR);
      int rr  = rem / XSTR;
      int cl  = rem - rr * XSTR;
      if (cl < 66) {
        int h = h0 - 1 + rr, wc = cl - 1;
        float v = 0.f;
        if ((unsigned)h < 64u && (unsigned)wc < 64u)
          v = x[((size_t)(b * CIN + ic0 + i) * H_ + h) * W_ + wc] * style[b * CIN + ic0 + i];
        xt[j] = v;
      }
    }
    // ---- stage weights: wt[oo][i*9+t], contiguous 72-float runs per oo ----
    for (int j = tid; j < OTILE * 72; j += 256) {
      int oo = j / 72, q = j - oo * 72;
      wt[j] = conv_w[(size_t)(o0 + oo) * (CIN * 9) + ic0 * 9 + q];
    }
    __syncthreads();

    #pragma unroll 1
    for (int i = 0; i < ICCH; ++i) {
      const float* xbi = &xt[i * (XROWS * XSTR) + r * XSTR + cg * 8];
      const float* wbi = &wt[oq * 8 * 72 + i * 9];
      #pragma unroll
      for (int ky = 0; ky < 3; ++ky) {
        float xr[10];
        #pragma unroll
        for (int q = 0; q < 10; ++q) xr[q] = xbi[ky * XSTR + q];
        #pragma unroll
        for (int kx = 0; kx < 3; ++kx) {
          #pragma unroll
          for (int oo = 0; oo < 8; ++oo) {
            float wv = wbi[oo * 72 + ky * 3 + kx];   // wave-broadcast read
            #pragma unroll
            for (int c = 0; c < 8; ++c) acc[oo][c] = fmaf(xr[c + kx], wv, acc[oo][c]);
          }
        }
      }
    }
    __syncthreads();
  }

  // ---- epilogue: demod scale, noise, bias, leaky-relu ----
  const float sn = scale_noise[0];
  const int row = h0 + r;
  float nz[8];
  #pragma unroll
  for (int c = 0; c < 8; ++c)
    nz[c] = sn * noise[((size_t)b * H_ + row) * W_ + cg * 8 + c];

  #pragma unroll
  for (int oo = 0; oo < 8; ++oo) {
    int o = o0 + oq * 8 + oo;
    float s  = scale_bo[b * COUT + o];
    float bv = bias[o];
    float* op = out + ((size_t)(b * COUT + o) * H_ + row) * W_ + cg * 8;
    #pragma unroll
    for (int c = 0; c < 8; ++c) {
      float v = fmaf(acc[oo][c], s, nz[c] + bv);
      op[c] = v > 0.f ? v : 0.2f * v;
    }
  }
}

extern "C" void kernel_launch(void* const* d_in, const int* in_sizes, int n_in,
                              void* d_out, int out_size, void* d_ws, size_t ws_size,
                              hipStream_t stream) {
  const float* x           = (const float*)d_in[0];
  const float* w           = (const float*)d_in[1];
  const float* noise       = (const float*)d_in[2];
  const float* style_w     = (const float*)d_in[3];
  const float* style_b     = (const float*)d_in[4];
  const float* conv_w      = (const float*)d_in[5];
  const float* scale_noise = (const float*)d_in[6];
  const float* bias        = (const float*)d_in[7];
  float* out = (float*)d_out;

  float* ws       = (float*)d_ws;
  float* style    = ws;            // B*CIN   = 8192 f
  float* scale_bo = ws + 8192;     // B*COUT  = 8192 f
  float* wsq      = ws + 16384;    // COUT*CIN = 262144 f   (total ~1.1 MB)

  style_kernel<<<2048, 256, 0, stream>>>(w, style_w, style_b, style);
  wsq_kernel<<<1024, 256, 0, stream>>>(conv_w, wsq);
  scale_kernel<<<2048, 256, 0, stream>>>(style, wsq, scale_bo);

  dim3 grid(H_ / HTILE, COUT / OTILE, B_);   // (8, 16, 16) = 2048 blocks
  conv_kernel<<<grid, 256, 0, stream>>>(x, style, conv_w, scale_bo,
                                        noise, scale_noise, bias, out);
}

// Round 2
// 634.610 us; speedup vs baseline: 7.3622x; 7.3622x over previous
//
#include <hip/hip_runtime.h>
#include <hip/hip_bf16.h>

// StyleBlock: B=16, C_IN=512, C_OUT=512, D_LATENT=512, H=W=64, K=3
// Round 2: implicit-GEMM bf16 MFMA (16x16x32), m97-style staging.
// out[m,o] = sum_k A[m,k]*W[o,k];  A = im2col(x * style), W batch-independent.
// Demod scale conv_coef*sigma_inv folded into epilogue. Fallback to fp32 path
// if ws_size too small for the bf16 pre-transposed tensors.

#define B_    16
#define CIN   512
#define COUT  512
#define DLAT  512
#define H_    64
#define W_    64

constexpr float LIN_COEF  = 0.04419417382415922f;   // 1/sqrt(512)
constexpr float CONV_COEF = 0.014731391274719739f;  // 1/sqrt(512*9)

typedef __attribute__((ext_vector_type(8))) short short8;
typedef __attribute__((ext_vector_type(4))) float f32x4;

__device__ __forceinline__ void gl2lds16(const void* g, void* l) {
  __builtin_amdgcn_global_load_lds(
      (const __attribute__((address_space(1))) unsigned*)g,
      (__attribute__((address_space(3))) unsigned*)l, 16, 0, 0);
}

// ---------------- style[b,c] = style_b[c] + lin_coef * <w[b,:], style_w[c,:]> ----
__global__ __launch_bounds__(256) void style_kernel(
    const float* __restrict__ w, const float* __restrict__ style_w,
    const float* __restrict__ style_b, float* __restrict__ style) {
  int gw   = blockIdx.x * 4 + (threadIdx.x >> 6);
  int lane = threadIdx.x & 63;
  int b = gw >> 9, c = gw & 511;
  const float* wp = w + b * DLAT;
  const float* sw = style_w + c * DLAT;
  float v = 0.f;
  for (int d = lane; d < DLAT; d += 64) v = fmaf(wp[d], sw[d], v);
  #pragma unroll
  for (int off = 32; off > 0; off >>= 1) v += __shfl_down(v, off, 64);
  if (lane == 0) style[b * CIN + c] = fmaf(v, LIN_COEF, style_b[c]);
}

// ---------------- wsq[o,i] = sum_k conv_w[o,i,k]^2 --------------------------------
__global__ __launch_bounds__(256) void wsq_kernel(
    const float* __restrict__ conv_w, float* __restrict__ wsq) {
  int idx = blockIdx.x * 256 + threadIdx.x;
  const float* p = conv_w + (size_t)idx * 9;
  float s = 0.f;
  #pragma unroll
  for (int t = 0; t < 9; ++t) s = fmaf(p[t], p[t], s);
  wsq[idx] = s;
}

// ---- scale_bo[b,o] = conv_coef * rsqrt(conv_coef^2 * sum_i style^2*wsq + eps) ----
__global__ __launch_bounds__(256) void scale_kernel(
    const float* __restrict__ style, const float* __restrict__ wsq,
    float* __restrict__ scale_bo) {
  int gw   = blockIdx.x * 4 + (threadIdx.x >> 6);
  int lane = threadIdx.x & 63;
  int b = gw >> 9, o = gw & 511;
  const float* st = style + b * CIN;
  const float* wq = wsq + o * CIN;
  float v = 0.f;
  for (int i = lane; i < CIN; i += 64) { float s = st[i]; v = fmaf(s * s, wq[i], v); }
  #pragma unroll
  for (int off = 32; off > 0; off >>= 1) v += __shfl_down(v, off, 64);
  if (lane == 0)
    scale_bo[b * COUT + o] = CONV_COEF * rsqrtf(fmaf(CONV_COEF * CONV_COEF, v, 1e-8f));
}

// ---------------- Wt[o][pos][ic] bf16 = conv_w[o][ic][pos] ------------------------
__global__ __launch_bounds__(256) void wt_pre_kernel(
    const float* __restrict__ conv_w, __hip_bfloat16* __restrict__ wtp) {
  __shared__ float lw[CIN * 9];
  int o = blockIdx.x, tid = threadIdx.x;
  for (int j = tid; j < CIN * 9; j += 256) lw[j] = conv_w[(size_t)o * (CIN * 9) + j];
  __syncthreads();
  for (int j = tid; j < CIN * 9; j += 256) {
    int pos = j >> 9, ic = j & 511;
    wtp[(size_t)o * (CIN * 9) + j] = __float2bfloat16(lw[ic * 9 + pos]);
  }
}

// ---------------- zero the halo border of x_t -------------------------------------
__global__ __launch_bounds__(256) void border_zero_kernel(__hip_bfloat16* __restrict__ xt) {
  int idx = blockIdx.x;            // 16 * 260 blocks
  int b = idx / 260, pb = idx - b * 260;
  int hh, ww;
  if (pb < 66)       { hh = 0;  ww = pb; }
  else if (pb < 132) { hh = 65; ww = pb - 66; }
  else if (pb < 196) { hh = pb - 132 + 1; ww = 0; }
  else               { hh = pb - 196 + 1; ww = 65; }
  unsigned* p = (unsigned*)(xt + (((size_t)b * 66 + hh) * 66 + ww) * CIN);
  p[threadIdx.x] = 0u;             // 256 * 4B = 512 bf16
}

// ------- x_t[b][h+1][w+1][ic] bf16 = x[b][ic][h][w] * style[b][ic] ----------------
#define LSTR 136
__global__ __launch_bounds__(256) void xmod_t_kernel(
    const float* __restrict__ x, const float* __restrict__ style,
    __hip_bfloat16* __restrict__ xt) {
  __shared__ __hip_bfloat16 ls[64 * LSTR];
  const int tid = threadIdx.x;
  const int ic0 = blockIdx.x * 128;       // 4 tiles
  const int h   = blockIdx.y;             // 64
  const int b   = blockIdx.z;             // 16
  for (int idx = tid; idx < 128 * 64; idx += 256) {
    int i = idx >> 6, w = idx & 63;
    float v = x[(((size_t)b * CIN + ic0 + i) * H_ + h) * W_ + w] * style[b * CIN + ic0 + i];
    ls[w * LSTR + i] = __float2bfloat16(v);
  }
  __syncthreads();
  for (int idx = tid; idx < 64 * 16; idx += 256) {
    int w = idx >> 4, part = idx & 15;
    __hip_bfloat16* dst = xt + (((size_t)b * 66 + h + 1) * 66 + (w + 1)) * CIN + ic0 + part * 8;
    *(short8*)dst = *(const short8*)(ls + w * LSTR + part * 8);
  }
}

// ---------------- main MFMA conv: 128(pix) x 128(o) tile --------------------------
// LDS: xs [4 rows][66 cols][32 ic] bf16 = 16896 B ;  wt3 [3 kx][128 o][32 ic] = 24576 B
#define SMEM_B 41472
__global__ __launch_bounds__(256) void conv_mfma(
    const __hip_bfloat16* __restrict__ xt, const __hip_bfloat16* __restrict__ wtp,
    const float* __restrict__ scale_bo, const float* __restrict__ noise,
    const float* __restrict__ scale_noise, const float* __restrict__ bias,
    float* __restrict__ out) {
  __shared__ __align__(16) char smem[SMEM_B];
  __hip_bfloat16* xs  = (__hip_bfloat16*)smem;            // 8448 el
  __hip_bfloat16* wt3 = (__hip_bfloat16*)(smem + 16896);  // 12288 el

  const int tid = threadIdx.x, lane = tid & 63, wid = tid >> 6;
  const int blockM = blockIdx.x;            // 0..511
  const int b  = blockM >> 5;
  const int h0 = (blockM & 31) << 1;        // 2 output rows per block
  const int o0 = blockIdx.y << 7;           // 0..3 -> o tile

  const int m0w = (wid & 1) << 6;           // wave m-offset (row h0 or h0+1)
  const int n0w = (wid >> 1) << 6;          // wave n-offset

  // ---- precompute staging offsets (element units) ----
  const size_t xbase = (size_t)b * 66 * 66 * CIN;
  int xg[5], xl[5], n_x = 0;
  for (int inst = wid; inst < 17; inst += 4) {
    int p = inst * 16 + (lane >> 2);
    int r = p / 66, c = p - r * 66;
    xg[n_x] = (p < 264) ? (((h0 + r) * 66 + c) * CIN + (lane & 3) * 8) : -1;
    xl[n_x] = inst * 512;
    ++n_x;
  }
  int wg[6], wl[6], n_w = 0;
  for (int inst = wid; inst < 24; inst += 4) {
    int kx = inst >> 3, og = inst & 7;
    int o  = o0 + og * 16 + (lane >> 2);
    wg[n_w] = o * (9 * CIN) + kx * CIN + (lane & 3) * 8;   // + ky*3*CIN + ic0 at use
    wl[n_w] = inst * 512;
    ++n_w;
  }

  f32x4 acc[4][4] = {};   // [ms][ns]
  const int kg   = (lane >> 4) * 8;
  const int mrow = lane & 15;

  for (int ic0 = 0; ic0 < CIN; ic0 += 32) {
    __syncthreads();                         // xs + wt3 free
    for (int t = 0; t < n_x; ++t)
      if (xg[t] >= 0)
        gl2lds16(xt + xbase + xg[t] + ic0, xs + xl[t]);

    for (int ky = 0; ky < 3; ++ky) {
      if (ky > 0) __syncthreads();           // wt3 free
      const int kofs = ky * (3 * CIN) + ic0;
      for (int t = 0; t < n_w; ++t)
        gl2lds16(wtp + wg[t] + kofs, wt3 + wl[t]);
      __syncthreads();                       // staged

      #pragma unroll
      for (int kx = 0; kx < 3; ++kx) {
        short8 af[4], bfr[4];
        #pragma unroll
        for (int ms = 0; ms < 4; ++ms) {
          int m = m0w + ms * 16 + mrow;
          int r = (m >> 6) + ky, c = (m & 63) + kx;
          af[ms] = *(const short8*)(xs + (r * 66 + c) * 32 + kg);
        }
        #pragma unroll
        for (int ns = 0; ns < 4; ++ns) {
          int ol = n0w + ns * 16 + mrow;
          bfr[ns] = *(const short8*)(wt3 + (kx * 128 + ol) * 32 + kg);
        }
        #pragma unroll
        for (int ms = 0; ms < 4; ++ms)
          #pragma unroll
          for (int ns = 0; ns < 4; ++ns)
            acc[ms][ns] = __builtin_amdgcn_mfma_f32_16x16x32_bf16(
                af[ms], bfr[ns], acc[ms][ns], 0, 0, 0);
      }
    }
  }

  // ---- epilogue: LDS transpose -> coalesced stores ----
  __syncthreads();
  float* ep = (float*)smem + wid * (64 * 17);   // per-wave 64x17 f32
  const float sn = scale_noise[0];
  const int h = h0 + (wid & 1);
  const float nz = sn * noise[((size_t)b * H_ + h) * W_ + lane];

  for (int ns = 0; ns < 4; ++ns) {
    #pragma unroll
    for (int ms = 0; ms < 4; ++ms) {
      int wrow = ms * 16 + (lane >> 4) * 4;
      #pragma unroll
      for (int rg = 0; rg < 4; ++rg)
        ep[(wrow + rg) * 17 + (lane & 15)] = acc[ms][ns][rg];
    }
    __syncthreads();
    #pragma unroll
    for (int oo = 0; oo < 16; ++oo) {
      int o = o0 + n0w + ns * 16 + oo;
      float v = ep[lane * 17 + oo];
      v = fmaf(v, scale_bo[b * COUT + o], nz + bias[o]);
      v = v > 0.f ? v : 0.2f * v;
      out[(((size_t)b * COUT + o) * H_ + h) * W_ + lane] = v;
    }
    __syncthreads();
  }
}

// =================== fallback fp32 direct conv (round-1, verified) ================
#define OTILE   32
#define HTILE   8
#define ICCH    8
#define XSTR    67
#define XROWS   10
__global__ __launch_bounds__(256) void conv_kernel(
    const float* __restrict__ x, const float* __restrict__ style,
    const float* __restrict__ conv_w, const float* __restrict__ scale_bo,
    const float* __restrict__ noise, const float* __restrict__ scale_noise,
    const float* __restrict__ bias, float* __restrict__ out) {
  __shared__ float xtile[ICCH * XROWS * XSTR];
  __shared__ float wt[OTILE * 72];
  const int tid = threadIdx.x;
  const int b  = blockIdx.z;
  const int o0 = blockIdx.y * OTILE;
  const int h0 = blockIdx.x * HTILE;
  const int lane = tid & 63, oq = tid >> 6;
  const int r  = lane >> 3;
  const int cg = lane & 7;
  float acc[8][8];
  #pragma unroll
  for (int a = 0; a < 8; ++a)
    #pragma unroll
    for (int c = 0; c < 8; ++c) acc[a][c] = 0.f;
  for (int ic0 = 0; ic0 < CIN; ic0 += ICCH) {
    for (int j = tid; j < ICCH * XROWS * XSTR; j += 256) {
      int i   = j / (XROWS * XSTR);
      int rem = j - i * (XROWS * XSTR);
      int rr  = rem / XSTR;
      int cl  = rem - rr * XSTR;
      if (cl < 66) {
        int h = h0 - 1 + rr, wc = cl - 1;
        float v = 0.f;
        if ((unsigned)h < 64u && (unsigned)wc < 64u)
          v = x[((size_t)(b * CIN + ic0 + i) * H_ + h) * W_ + wc] * style[b * CIN + ic0 + i];
        xtile[j] = v;
      }
    }
    for (int j = tid; j < OTILE * 72; j += 256) {
      int oo = j / 72, q = j - oo * 72;
      wt[j] = conv_w[(size_t)(o0 + oo) * (CIN * 9) + ic0 * 9 + q];
    }
    __syncthreads();
    #pragma unroll 1
    for (int i = 0; i < ICCH; ++i) {
      const float* xbi = &xtile[i * (XROWS * XSTR) + r * XSTR + cg * 8];
      const float* wbi = &wt[oq * 8 * 72 + i * 9];
      #pragma unroll
      for (int ky = 0; ky < 3; ++ky) {
        float xr[10];
        #pragma unroll
        for (int q = 0; q < 10; ++q) xr[q] = xbi[ky * XSTR + q];
        #pragma unroll
        for (int kx = 0; kx < 3; ++kx) {
          #pragma unroll
          for (int oo = 0; oo < 8; ++oo) {
            float wv = wbi[oo * 72 + ky * 3 + kx];
            #pragma unroll
            for (int c = 0; c < 8; ++c) acc[oo][c] = fmaf(xr[c + kx], wv, acc[oo][c]);
          }
        }
      }
    }
    __syncthreads();
  }
  const float sn = scale_noise[0];
  const int row = h0 + r;
  float nz[8];
  #pragma unroll
  for (int c = 0; c < 8; ++c)
    nz[c] = sn * noise[((size_t)b * H_ + row) * W_ + cg * 8 + c];
  #pragma unroll
  for (int oo = 0; oo < 8; ++oo) {
    int o = o0 + oq * 8 + oo;
    float s  = scale_bo[b * COUT + o];
    float bv = bias[o];
    float* op = out + ((size_t)(b * COUT + o) * H_ + row) * W_ + cg * 8;
    #pragma unroll
    for (int c = 0; c < 8; ++c) {
      float v = fmaf(acc[oo][c], s, nz[c] + bv);
      op[c] = v > 0.f ? v : 0.2f * v;
    }
  }
}

// ================================ launch ==========================================
extern "C" void kernel_launch(void* const* d_in, const int* in_sizes, int n_in,
                              void* d_out, int out_size, void* d_ws, size_t ws_size,
                              hipStream_t stream) {
  const float* x           = (const float*)d_in[0];
  const float* w           = (const float*)d_in[1];
  const float* noise       = (const float*)d_in[2];
  const float* style_w     = (const float*)d_in[3];
  const float* style_b     = (const float*)d_in[4];
  const float* conv_w      = (const float*)d_in[5];
  const float* scale_noise = (const float*)d_in[6];
  const float* bias        = (const float*)d_in[7];
  float* out = (float*)d_out;

  float* wsf      = (float*)d_ws;
  float* style    = wsf;            // 8192 f
  float* scale_bo = wsf + 8192;     // 8192 f
  float* wsq      = wsf + 16384;    // 262144 f -> ends at byte 1114112
  const size_t WTP_OFF = 1114112;                    // bytes
  const size_t XT_OFF  = WTP_OFF + (size_t)COUT * 9 * CIN * 2;          // +4718592
  const size_t NEED    = XT_OFF + (size_t)B_ * 66 * 66 * CIN * 2;       // 77201408

  style_kernel<<<2048, 256, 0, stream>>>(w, style_w, style_b, style);
  wsq_kernel<<<1024, 256, 0, stream>>>(conv_w, wsq);
  scale_kernel<<<2048, 256, 0, stream>>>(style, wsq, scale_bo);

  if (ws_size >= NEED) {
    __hip_bfloat16* wtp = (__hip_bfloat16*)((char*)d_ws + WTP_OFF);
    __hip_bfloat16* xtp = (__hip_bfloat16*)((char*)d_ws + XT_OFF);
    wt_pre_kernel<<<512, 256, 0, stream>>>(conv_w, wtp);
    border_zero_kernel<<<16 * 260, 256, 0, stream>>>(xtp);
    dim3 gx(4, 64, 16);
    xmod_t_kernel<<<gx, 256, 0, stream>>>(x, style, xtp);
    dim3 grid(512, 4, 1);
    conv_mfma<<<grid, 256, 0, stream>>>(xtp, wtp, scale_bo, noise, scale_noise, bias, out);
  } else {
    dim3 grid(H_ / HTILE, COUT / OTILE, B_);
    conv_kernel<<<grid, 256, 0, stream>>>(x, style, conv_w, scale_bo,
                                          noise, scale_noise, bias, out);
  }
}

// Round 3
// 540.724 us; speedup vs baseline: 8.6406x; 1.1736x over previous
//
#include <hip/hip_runtime.h>
#include <hip/hip_bf16.h>

// StyleBlock: B=16, C_IN=512, C_OUT=512, D_LATENT=512, H=W=64, K=3
// Round 3: implicit-GEMM bf16 MFMA. A (style-modulated x, im2col) staged in LDS
// with XOR bank-swizzle; B (weights) read straight from L2 in coalesced
// [chunk][pos][kq][o][8ic] layout => LDS:MFMA cycle ratio 0.75 (MFMA-bound).
// 2 barriers per 32-ic chunk. Pre-chain fused into 2 kernels.

#define B_    16
#define CIN   512
#define COUT  512
#define DLAT  512
#define H_    64
#define W_    64

constexpr float LIN_COEF  = 0.04419417382415922f;   // 1/sqrt(512)
constexpr float CONV_COEF = 0.014731391274719739f;  // 1/sqrt(512*9)

typedef __attribute__((ext_vector_type(8))) short short8;
typedef __attribute__((ext_vector_type(4))) float f32x4;

__device__ __forceinline__ void gl2lds16(const void* g, void* l) {
  __builtin_amdgcn_global_load_lds(
      (const __attribute__((address_space(1))) unsigned*)g,
      (__attribute__((address_space(3))) unsigned*)l, 16, 0, 0);
}

// =============== fused pre-kernel 1: style | wsq | wtp2 | border-zero =============
__global__ __launch_bounds__(256) void pre1(
    const float* __restrict__ w, const float* __restrict__ style_w,
    const float* __restrict__ style_b, const float* __restrict__ conv_w,
    float* __restrict__ style, float* __restrict__ wsq,
    __hip_bfloat16* __restrict__ wtp2, __hip_bfloat16* __restrict__ xt) {
  __shared__ float lw[CIN * 9];
  const int bid = blockIdx.x, tid = threadIdx.x;
  if (bid < 2048) {            // ---- style[b,c] ----
    int gw = bid * 4 + (tid >> 6), lane = tid & 63;
    int b = gw >> 9, c = gw & 511;
    const float* wp = w + b * DLAT;
    const float* sw = style_w + c * DLAT;
    float v = 0.f;
    for (int d = lane; d < DLAT; d += 64) v = fmaf(wp[d], sw[d], v);
    #pragma unroll
    for (int off = 32; off > 0; off >>= 1) v += __shfl_down(v, off, 64);
    if (lane == 0) style[b * CIN + c] = fmaf(v, LIN_COEF, style_b[c]);
  } else if (bid < 3072) {     // ---- wsq[o,i] ----
    int idx = (bid - 2048) * 256 + tid;
    const float* p = conv_w + (size_t)idx * 9;
    float s = 0.f;
    #pragma unroll
    for (int t = 0; t < 9; ++t) s = fmaf(p[t], p[t], s);
    wsq[idx] = s;
  } else if (bid < 3584) {     // ---- wtp2[chunk][pos][kq][o][8] bf16 ----
    int o = bid - 3072;
    for (int j = tid; j < CIN * 9; j += 256) lw[j] = conv_w[(size_t)o * (CIN * 9) + j];
    __syncthreads();
    for (int g = tid; g < 576; g += 256) {   // 16 chunks * 9 pos * 4 kq
      int chunk = g / 36, rem = g - chunk * 36, pos = rem >> 2, kqq = rem & 3;
      short8 v;
      #pragma unroll
      for (int e = 0; e < 8; ++e) {
        int ic = chunk * 32 + kqq * 8 + e;
        ((__hip_bfloat16*)&v)[e] = __float2bfloat16(lw[ic * 9 + pos]);
      }
      ((short8*)wtp2)[(size_t)g * 512 + o] = v;
    }
  } else {                     // ---- zero x_t halo border ----
    int idx = bid - 3584;      // 16*260
    int b = idx / 260, pb = idx - b * 260;
    int hh, ww;
    if (pb < 66)       { hh = 0;  ww = pb; }
    else if (pb < 132) { hh = 65; ww = pb - 66; }
    else if (pb < 196) { hh = pb - 132 + 1; ww = 0; }
    else               { hh = pb - 196 + 1; ww = 65; }
    unsigned* p = (unsigned*)(xt + (((size_t)b * 66 + hh) * 66 + ww) * CIN);
    p[tid] = 0u;
  }
}

// =============== fused pre-kernel 2: scale_bo | xmod transpose ====================
#define LSTR 136
__global__ __launch_bounds__(256) void pre2(
    const float* __restrict__ x, const float* __restrict__ style,
    const float* __restrict__ wsq, float* __restrict__ scale_bo,
    __hip_bfloat16* __restrict__ xt) {
  __shared__ __align__(16) char sm2[64 * LSTR * 2];
  const int bid = blockIdx.x, tid = threadIdx.x;
  if (bid < 2048) {            // ---- scale_bo[b,o] ----
    int gw = bid * 4 + (tid >> 6), lane = tid & 63;
    int b = gw >> 9, o = gw & 511;
    const float* st = style + b * CIN;
    const float* wq = wsq + o * CIN;
    float v = 0.f;
    for (int i = lane; i < CIN; i += 64) { float s = st[i]; v = fmaf(s * s, wq[i], v); }
    #pragma unroll
    for (int off = 32; off > 0; off >>= 1) v += __shfl_down(v, off, 64);
    if (lane == 0)
      scale_bo[b * COUT + o] = CONV_COEF * rsqrtf(fmaf(CONV_COEF * CONV_COEF, v, 1e-8f));
  } else {                     // ---- x_t[b][h+1][w+1][ic] = bf16(x * style) ----
    int idx = bid - 2048;      // 16*64*4
    int b = idx >> 8, rem = idx & 255, h = rem >> 2, ic0 = (rem & 3) * 128;
    __hip_bfloat16* ls = (__hip_bfloat16*)sm2;
    for (int j = tid; j < 128 * 64; j += 256) {
      int i = j >> 6, ww = j & 63;
      float v = x[(((size_t)b * CIN + ic0 + i) * H_ + h) * W_ + ww] * style[b * CIN + ic0 + i];
      ls[ww * LSTR + i] = __float2bfloat16(v);
    }
    __syncthreads();
    for (int j = tid; j < 64 * 16; j += 256) {
      int ww = j >> 4, part = j & 15;
      __hip_bfloat16* dst = xt + (((size_t)b * 66 + h + 1) * 66 + (ww + 1)) * CIN + ic0 + part * 8;
      *(short8*)dst = *(const short8*)(ls + ww * LSTR + part * 8);
    }
  }
}

// =============== main conv: block = 4 rows x 64 px x 64 o, 4 waves ================
// LDS: A-tile only: 6 input rows x 66 px x 32 ic bf16, XOR-swizzled = 25344 B.
// Wave w computes output row h0+w (64 px) x 64 o as 4x4 MFMA 16x16x32 frags.
__global__ __launch_bounds__(256, 3) void conv_mfma(
    const __hip_bfloat16* __restrict__ xt, const __hip_bfloat16* __restrict__ wtp2,
    const float* __restrict__ scale_bo, const float* __restrict__ noise,
    const float* __restrict__ scale_noise, const float* __restrict__ bias,
    float* __restrict__ out) {
  __shared__ __align__(16) char smem[25344];

  const int tid = threadIdx.x, lane = tid & 63, wid = tid >> 6;
  const int mrow = lane & 15, kq = lane >> 4;
  const int b  = blockIdx.x >> 4;
  const int h0 = (blockIdx.x & 15) << 2;
  const int o0 = blockIdx.y << 6;
  const int h  = h0 + wid;

  // ---- staging gather offsets: LDS granule t holds pixel p=t>>2, slot s=t&3,
  //      containing global ic-group q = s ^ ((p>>1)&3)  (bank swizzle) ----
  const size_t xbase = ((size_t)(b * 66 + h0)) * (66 * 512);
  int xoff[7];
  #pragma unroll
  for (int i = 0; i < 7; ++i) {
    int slot = wid + i * 4;
    int t = slot * 64 + lane;
    if (t < 1584) {            // 6*66 px * 4 granules
      int p = t >> 2, s = t & 3;
      int q = s ^ ((p >> 1) & 3);
      xoff[i] = p * 512 + q * 8;
    } else xoff[i] = -1;
  }

  f32x4 acc[4][4] = {};        // [ms][ns]
  int pbase[4];
  #pragma unroll
  for (int ms = 0; ms < 4; ++ms) pbase[ms] = wid * 66 + ms * 16 + mrow;

  const short8* bbase = (const short8*)wtp2 + (kq * 512 + o0 + mrow);

  for (int ic0 = 0; ic0 < CIN; ic0 += 32) {
    __syncthreads();                           // xs free
    #pragma unroll
    for (int i = 0; i < 7; ++i)
      if (xoff[i] >= 0)
        gl2lds16(xt + xbase + xoff[i] + ic0, smem + (wid + i * 4) * 1024);
    __syncthreads();                           // xs ready (vmcnt drain)

    const int ch9 = (ic0 >> 5) * 9;
    #pragma unroll
    for (int ky = 0; ky < 3; ++ky) {
      #pragma unroll
      for (int kx = 0; kx < 3; ++kx) {
        const short8* bp = bbase + (size_t)(ch9 + ky * 3 + kx) * 2048;
        short8 bf0 = bp[0], bf1 = bp[16], bf2 = bp[32], bf3 = bp[48];
        short8 af[4];
        #pragma unroll
        for (int ms = 0; ms < 4; ++ms) {
          int p = pbase[ms] + ky * 66 + kx;
          int s = kq ^ ((p >> 1) & 3);
          af[ms] = *(const short8*)(smem + p * 64 + s * 16);
        }
        #pragma unroll
        for (int ms = 0; ms < 4; ++ms) {
          acc[ms][0] = __builtin_amdgcn_mfma_f32_16x16x32_bf16(af[ms], bf0, acc[ms][0], 0, 0, 0);
          acc[ms][1] = __builtin_amdgcn_mfma_f32_16x16x32_bf16(af[ms], bf1, acc[ms][1], 0, 0, 0);
          acc[ms][2] = __builtin_amdgcn_mfma_f32_16x16x32_bf16(af[ms], bf2, acc[ms][2], 0, 0, 0);
          acc[ms][3] = __builtin_amdgcn_mfma_f32_16x16x32_bf16(af[ms], bf3, acc[ms][3], 0, 0, 0);
        }
      }
    }
  }

  // ---- epilogue: per-wave LDS transpose -> coalesced stores ----
  __syncthreads();                             // all frag reads of smem done
  float* ep = (float*)smem + wid * 1088;       // 64 x 17 f32 per wave
  const float sn = scale_noise[0];
  const float nz = sn * noise[((size_t)b * H_ + h) * W_ + lane];

  for (int ns = 0; ns < 4; ++ns) {
    #pragma unroll
    for (int ms = 0; ms < 4; ++ms) {
      int prow = ms * 16 + kq * 4;             // D row = pixel index
      #pragma unroll
      for (int rg = 0; rg < 4; ++rg)
        ep[(prow + rg) * 17 + mrow] = acc[ms][ns][rg];
    }
    #pragma unroll
    for (int oo = 0; oo < 16; ++oo) {
      int o = o0 + ns * 16 + oo;               // wave-uniform
      float v = ep[lane * 17 + oo];
      v = fmaf(v, scale_bo[b * COUT + o], nz + bias[o]);
      v = v > 0.f ? v : 0.2f * v;
      out[(((size_t)b * COUT + o) * H_ + h) * W_ + lane] = v;
    }
  }
}

// =================== fallback fp32 direct conv (round-1, verified) ================
__global__ __launch_bounds__(256) void style_kernel(
    const float* __restrict__ w, const float* __restrict__ style_w,
    const float* __restrict__ style_b, float* __restrict__ style) {
  int gw = blockIdx.x * 4 + (threadIdx.x >> 6);
  int lane = threadIdx.x & 63;
  int b = gw >> 9, c = gw & 511;
  const float* wp = w + b * DLAT;
  const float* sw = style_w + c * DLAT;
  float v = 0.f;
  for (int d = lane; d < DLAT; d += 64) v = fmaf(wp[d], sw[d], v);
  #pragma unroll
  for (int off = 32; off > 0; off >>= 1) v += __shfl_down(v, off, 64);
  if (lane == 0) style[b * CIN + c] = fmaf(v, LIN_COEF, style_b[c]);
}
__global__ __launch_bounds__(256) void wsq_kernel(
    const float* __restrict__ conv_w, float* __restrict__ wsq) {
  int idx = blockIdx.x * 256 + threadIdx.x;
  const float* p = conv_w + (size_t)idx * 9;
  float s = 0.f;
  #pragma unroll
  for (int t = 0; t < 9; ++t) s = fmaf(p[t], p[t], s);
  wsq[idx] = s;
}
__global__ __launch_bounds__(256) void scale_kernel(
    const float* __restrict__ style, const float* __restrict__ wsq,
    float* __restrict__ scale_bo) {
  int gw = blockIdx.x * 4 + (threadIdx.x >> 6);
  int lane = threadIdx.x & 63;
  int b = gw >> 9, o = gw & 511;
  const float* st = style + b * CIN;
  const float* wq = wsq + o * CIN;
  float v = 0.f;
  for (int i = lane; i < CIN; i += 64) { float s = st[i]; v = fmaf(s * s, wq[i], v); }
  #pragma unroll
  for (int off = 32; off > 0; off >>= 1) v += __shfl_down(v, off, 64);
  if (lane == 0)
    scale_bo[b * COUT + o] = CONV_COEF * rsqrtf(fmaf(CONV_COEF * CONV_COEF, v, 1e-8f));
}
#define OTILE 32
#define HTILE 8
#define ICCH  8
#define XSTR  67
#define XROWS 10
__global__ __launch_bounds__(256) void conv_kernel(
    const float* __restrict__ x, const float* __restrict__ style,
    const float* __restrict__ conv_w, const float* __restrict__ scale_bo,
    const float* __restrict__ noise, const float* __restrict__ scale_noise,
    const float* __restrict__ bias, float* __restrict__ out) {
  __shared__ float xtile[ICCH * XROWS * XSTR];
  __shared__ float wt[OTILE * 72];
  const int tid = threadIdx.x;
  const int b = blockIdx.z, o0 = blockIdx.y * OTILE, h0 = blockIdx.x * HTILE;
  const int lane = tid & 63, oq = tid >> 6;
  const int r = lane >> 3, cg = lane & 7;
  float acc[8][8];
  #pragma unroll
  for (int a = 0; a < 8; ++a)
    #pragma unroll
    for (int c = 0; c < 8; ++c) acc[a][c] = 0.f;
  for (int ic0 = 0; ic0 < CIN; ic0 += ICCH) {
    for (int j = tid; j < ICCH * XROWS * XSTR; j += 256) {
      int i = j / (XROWS * XSTR);
      int rem = j - i * (XROWS * XSTR);
      int rr = rem / XSTR, cl = rem - rr * XSTR;
      if (cl < 66) {
        int hh = h0 - 1 + rr, wc = cl - 1;
        float v = 0.f;
        if ((unsigned)hh < 64u && (unsigned)wc < 64u)
          v = x[((size_t)(b * CIN + ic0 + i) * H_ + hh) * W_ + wc] * style[b * CIN + ic0 + i];
        xtile[j] = v;
      }
    }
    for (int j = tid; j < OTILE * 72; j += 256) {
      int oo = j / 72, q = j - oo * 72;
      wt[j] = conv_w[(size_t)(o0 + oo) * (CIN * 9) + ic0 * 9 + q];
    }
    __syncthreads();
    #pragma unroll 1
    for (int i = 0; i < ICCH; ++i) {
      const float* xbi = &xtile[i * (XROWS * XSTR) + r * XSTR + cg * 8];
      const float* wbi = &wt[oq * 8 * 72 + i * 9];
      #pragma unroll
      for (int ky = 0; ky < 3; ++ky) {
        float xr[10];
        #pragma unroll
        for (int q = 0; q < 10; ++q) xr[q] = xbi[ky * XSTR + q];
        #pragma unroll
        for (int kx = 0; kx < 3; ++kx) {
          #pragma unroll
          for (int oo = 0; oo < 8; ++oo) {
            float wv = wbi[oo * 72 + ky * 3 + kx];
            #pragma unroll
            for (int c = 0; c < 8; ++c) acc[oo][c] = fmaf(xr[c + kx], wv, acc[oo][c]);
          }
        }
      }
    }
    __syncthreads();
  }
  const float sn = scale_noise[0];
  const int row = h0 + r;
  float nz[8];
  #pragma unroll
  for (int c = 0; c < 8; ++c)
    nz[c] = sn * noise[((size_t)b * H_ + row) * W_ + cg * 8 + c];
  #pragma unroll
  for (int oo = 0; oo < 8; ++oo) {
    int o = o0 + oq * 8 + oo;
    float s = scale_bo[b * COUT + o];
    float bv = bias[o];
    float* op = out + ((size_t)(b * COUT + o) * H_ + row) * W_ + cg * 8;
    #pragma unroll
    for (int c = 0; c < 8; ++c) {
      float v = fmaf(acc[oo][c], s, nz[c] + bv);
      op[c] = v > 0.f ? v : 0.2f * v;
    }
  }
}

// ================================ launch ==========================================
extern "C" void kernel_launch(void* const* d_in, const int* in_sizes, int n_in,
                              void* d_out, int out_size, void* d_ws, size_t ws_size,
                              hipStream_t stream) {
  const float* x           = (const float*)d_in[0];
  const float* w           = (const float*)d_in[1];
  const float* noise       = (const float*)d_in[2];
  const float* style_w     = (const float*)d_in[3];
  const float* style_b     = (const float*)d_in[4];
  const float* conv_w      = (const float*)d_in[5];
  const float* scale_noise = (const float*)d_in[6];
  const float* bias        = (const float*)d_in[7];
  float* out = (float*)d_out;

  float* wsf      = (float*)d_ws;
  float* style    = wsf;            // 8192 f
  float* scale_bo = wsf + 8192;     // 8192 f
  float* wsq      = wsf + 16384;    // 262144 f -> ends at byte 1114112
  const size_t WTP_OFF = 1114112;
  const size_t XT_OFF  = WTP_OFF + (size_t)COUT * 9 * CIN * 2;      // +4718592
  const size_t NEED    = XT_OFF + (size_t)B_ * 66 * 66 * CIN * 2;   // 77201408

  if (ws_size >= NEED) {
    __hip_bfloat16* wtp2 = (__hip_bfloat16*)((char*)d_ws + WTP_OFF);
    __hip_bfloat16* xtp  = (__hip_bfloat16*)((char*)d_ws + XT_OFF);
    pre1<<<3584 + 16 * 260, 256, 0, stream>>>(w, style_w, style_b, conv_w,
                                              style, wsq, wtp2, xtp);
    pre2<<<2048 + 4096, 256, 0, stream>>>(x, style, wsq, scale_bo, xtp);
    dim3 grid(256, 8, 1);
    conv_mfma<<<grid, 256, 0, stream>>>(xtp, wtp2, scale_bo, noise,
                                        scale_noise, bias, out);
  } else {
    style_kernel<<<2048, 256, 0, stream>>>(w, style_w, style_b, style);
    wsq_kernel<<<1024, 256, 0, stream>>>(conv_w, wsq);
    scale_kernel<<<2048, 256, 0, stream>>>(style, wsq, scale_bo);
    dim3 grid(H_ / HTILE, COUT / OTILE, B_);
    conv_kernel<<<grid, 256, 0, stream>>>(x, style, conv_w, scale_bo,
                                          noise, scale_noise, bias, out);
  }
}

// Round 4
// 529.525 us; speedup vs baseline: 8.8233x; 1.0211x over previous
//
#include <hip/hip_runtime.h>
#include <hip/hip_bf16.h>

// StyleBlock: B=16, C_IN=512, C_OUT=512, D_LATENT=512, H=W=64, K=3
// Round 4: implicit-GEMM bf16 MFMA. Wave tile 128px x 64o (B L2 traffic halves:
// B-traffic = M*N*K*2/M_wave). A staged in LDS XOR-swizzled; B from L2 in
// [chunk][pos][kq][o][8ic] layout. Pre-chain: p1={style,wsq} tiny,
// p2={scale,wtp2,border,xmod-vectorized} all-parallel.

#define B_    16
#define CIN   512
#define COUT  512
#define DLAT  512
#define H_    64
#define W_    64

constexpr float LIN_COEF  = 0.04419417382415922f;   // 1/sqrt(512)
constexpr float CONV_COEF = 0.014731391274719739f;  // 1/sqrt(512*9)

typedef __attribute__((ext_vector_type(8))) short short8;
typedef __attribute__((ext_vector_type(4))) float f32x4;

__device__ __forceinline__ void gl2lds16(const void* g, void* l) {
  __builtin_amdgcn_global_load_lds(
      (const __attribute__((address_space(1))) unsigned*)g,
      (__attribute__((address_space(3))) unsigned*)l, 16, 0, 0);
}

// =============== pre-kernel 1: style | wsq  (3072 blocks) =========================
__global__ __launch_bounds__(256) void pre1(
    const float* __restrict__ w, const float* __restrict__ style_w,
    const float* __restrict__ style_b, const float* __restrict__ conv_w,
    float* __restrict__ style, float* __restrict__ wsq) {
  const int bid = blockIdx.x, tid = threadIdx.x;
  if (bid < 2048) {            // ---- style[b,c] ----
    int gw = bid * 4 + (tid >> 6), lane = tid & 63;
    int b = gw >> 9, c = gw & 511;
    const float* wp = w + b * DLAT;
    const float* sw = style_w + c * DLAT;
    float v = 0.f;
    for (int d = lane; d < DLAT; d += 64) v = fmaf(wp[d], sw[d], v);
    #pragma unroll
    for (int off = 32; off > 0; off >>= 1) v += __shfl_down(v, off, 64);
    if (lane == 0) style[b * CIN + c] = fmaf(v, LIN_COEF, style_b[c]);
  } else {                     // ---- wsq[o,i] ----
    int idx = (bid - 2048) * 256 + tid;
    const float* p = conv_w + (size_t)idx * 9;
    float s = 0.f;
    #pragma unroll
    for (int t = 0; t < 9; ++t) s = fmaf(p[t], p[t], s);
    wsq[idx] = s;
  }
}

// ====== pre-kernel 2: scale_bo | wtp2 | border-zero | xmod  (10816 blocks) ========
#define LSTR 136
__global__ __launch_bounds__(256) void pre2(
    const float* __restrict__ x, const float* __restrict__ style,
    const float* __restrict__ wsq, const float* __restrict__ conv_w,
    float* __restrict__ scale_bo, __hip_bfloat16* __restrict__ wtp2,
    __hip_bfloat16* __restrict__ xt) {
  __shared__ __align__(16) char sm2[18432];
  const int bid = blockIdx.x, tid = threadIdx.x;
  if (bid < 2048) {            // ---- scale_bo[b,o] ----
    int gw = bid * 4 + (tid >> 6), lane = tid & 63;
    int b = gw >> 9, o = gw & 511;
    const float* st = style + b * CIN;
    const float* wq = wsq + o * CIN;
    float v = 0.f;
    for (int i = lane; i < CIN; i += 64) { float s = st[i]; v = fmaf(s * s, wq[i], v); }
    #pragma unroll
    for (int off = 32; off > 0; off >>= 1) v += __shfl_down(v, off, 64);
    if (lane == 0)
      scale_bo[b * COUT + o] = CONV_COEF * rsqrtf(fmaf(CONV_COEF * CONV_COEF, v, 1e-8f));
  } else if (bid < 2560) {     // ---- wtp2[chunk][pos][kq][o][8] bf16 ----
    int o = bid - 2048;
    float* lw = (float*)sm2;
    for (int j = tid; j < CIN * 9; j += 256) lw[j] = conv_w[(size_t)o * (CIN * 9) + j];
    __syncthreads();
    for (int g = tid; g < 576; g += 256) {   // 16 chunks * 9 pos * 4 kq
      int chunk = g / 36, rem = g - chunk * 36, pos = rem >> 2, kqq = rem & 3;
      short8 v;
      #pragma unroll
      for (int e = 0; e < 8; ++e) {
        int ic = chunk * 32 + kqq * 8 + e;
        ((__hip_bfloat16*)&v)[e] = __float2bfloat16(lw[ic * 9 + pos]);
      }
      ((short8*)wtp2)[(size_t)g * 512 + o] = v;
    }
  } else if (bid < 6720) {     // ---- zero x_t halo border ----
    int idx = bid - 2560;      // 16*260
    int b = idx / 260, pb = idx - b * 260;
    int hh, ww;
    if (pb < 66)       { hh = 0;  ww = pb; }
    else if (pb < 132) { hh = 65; ww = pb - 66; }
    else if (pb < 196) { hh = pb - 132 + 1; ww = 0; }
    else               { hh = pb - 196 + 1; ww = 65; }
    unsigned* p = (unsigned*)(xt + (((size_t)b * 66 + hh) * 66 + ww) * CIN);
    p[tid] = 0u;
  } else {                     // ---- x_t[b][h+1][w+1][ic] = bf16(x * style) ----
    int idx = bid - 6720;      // 16*64*4
    int b = idx >> 8, rem = idx & 255, h = rem >> 2, ic0 = (rem & 3) * 128;
    __hip_bfloat16* ls = (__hip_bfloat16*)sm2;      // [64 w][LSTR ic]
    for (int j = tid; j < 2048; j += 256) {         // 128 ic x 16 w-quads
      int i = j >> 4, wq = j & 15;
      const float4 xv = *(const float4*)&x[(((size_t)b * CIN + ic0 + i) * H_ + h) * W_ + wq * 4];
      float st = style[b * CIN + ic0 + i];
      ls[(wq * 4 + 0) * LSTR + i] = __float2bfloat16(xv.x * st);
      ls[(wq * 4 + 1) * LSTR + i] = __float2bfloat16(xv.y * st);
      ls[(wq * 4 + 2) * LSTR + i] = __float2bfloat16(xv.z * st);
      ls[(wq * 4 + 3) * LSTR + i] = __float2bfloat16(xv.w * st);
    }
    __syncthreads();
    for (int j = tid; j < 1024; j += 256) {
      int ww = j >> 4, part = j & 15;
      __hip_bfloat16* dst = xt + (((size_t)b * 66 + h + 1) * 66 + (ww + 1)) * CIN + ic0 + part * 8;
      *(short8*)dst = *(const short8*)(ls + ww * LSTR + part * 8);
    }
  }
}

// =============== main conv: block = 8 rows x 64 px x 64 o, 4 waves ================
// Wave tile: 2 rows (128 px) x 64 o = 8x4 MFMA 16x16x32 frags, acc 128 VGPR.
// LDS A-tile: 10 input rows x 66 px x 32 ic bf16, XOR-swizzled = 42240 B.
__global__ __launch_bounds__(256, 2) void conv_mfma(
    const __hip_bfloat16* __restrict__ xt, const __hip_bfloat16* __restrict__ wtp2,
    const float* __restrict__ scale_bo, const float* __restrict__ noise,
    const float* __restrict__ scale_noise, const float* __restrict__ bias,
    float* __restrict__ out) {
  __shared__ __align__(16) char smem[42240];

  const int tid = threadIdx.x, lane = tid & 63, wid = tid >> 6;
  const int mrow = lane & 15, kq = lane >> 4;
  const int b  = blockIdx.x >> 3;
  const int h0 = (blockIdx.x & 7) << 3;      // 8 output rows per block
  const int o0 = blockIdx.y << 6;
  const int r0 = h0 + (wid << 1);            // wave's first output row

  // ---- staging offsets: granule t: pixel p=t>>2, slot s=t&3, holds ic-group
  //      q = s ^ ((p>>1)&3)  (XOR bank swizzle) ----
  const size_t xbase = ((size_t)(b * 66 + h0)) * (66 * 512);
  int xoff[11];
  #pragma unroll
  for (int i = 0; i < 11; ++i) {
    int slot = wid + i * 4;
    int t = slot * 64 + lane;
    if (t < 2640) {            // 10 rows * 66 px * 4 granules
      int p = t >> 2, s = t & 3;
      int q = s ^ ((p >> 1) & 3);
      xoff[i] = p * 512 + q * 8;
    } else xoff[i] = -1;
  }

  f32x4 acc[8][4] = {};        // [ms][ns]
  int pbase[8];
  #pragma unroll
  for (int ms = 0; ms < 8; ++ms)
    pbase[ms] = ((wid << 1) + (ms >> 2)) * 66 + (ms & 3) * 16 + mrow;

  const short8* bbase = (const short8*)wtp2 + (kq * 512 + o0 + mrow);

  for (int ic0 = 0; ic0 < CIN; ic0 += 32) {
    __syncthreads();                           // A-tile free
    #pragma unroll
    for (int i = 0; i < 11; ++i)
      if (xoff[i] >= 0)
        gl2lds16(xt + xbase + xoff[i] + ic0, smem + (wid + i * 4) * 1024);
    __syncthreads();                           // A-tile ready

    const int ch9 = (ic0 >> 5) * 9;
    #pragma unroll
    for (int ky = 0; ky < 3; ++ky) {
      #pragma unroll
      for (int kx = 0; kx < 3; ++kx) {
        const short8* bp = bbase + (size_t)(ch9 + ky * 3 + kx) * 2048;
        short8 bf0 = bp[0], bf1 = bp[16], bf2 = bp[32], bf3 = bp[48];
        short8 af[8];
        #pragma unroll
        for (int ms = 0; ms < 8; ++ms) {
          int p = pbase[ms] + ky * 66 + kx;
          int s = kq ^ ((p >> 1) & 3);
          af[ms] = *(const short8*)(smem + p * 64 + s * 16);
        }
        #pragma unroll
        for (int ms = 0; ms < 8; ++ms) {
          acc[ms][0] = __builtin_amdgcn_mfma_f32_16x16x32_bf16(af[ms], bf0, acc[ms][0], 0, 0, 0);
          acc[ms][1] = __builtin_amdgcn_mfma_f32_16x16x32_bf16(af[ms], bf1, acc[ms][1], 0, 0, 0);
          acc[ms][2] = __builtin_amdgcn_mfma_f32_16x16x32_bf16(af[ms], bf2, acc[ms][2], 0, 0, 0);
          acc[ms][3] = __builtin_amdgcn_mfma_f32_16x16x32_bf16(af[ms], bf3, acc[ms][3], 0, 0, 0);
        }
      }
    }
  }

  // ---- epilogue: per-wave LDS transpose -> coalesced stores ----
  __syncthreads();                             // all frag reads done
  float* ep = (float*)smem + wid * 1088;       // 64 x 17 f32 per wave (private)
  const float sn = scale_noise[0];

  #pragma unroll
  for (int r = 0; r < 2; ++r) {
    const int h = r0 + r;
    const float nz = sn * noise[((size_t)b * H_ + h) * W_ + lane];
    for (int ns = 0; ns < 4; ++ns) {
      #pragma unroll
      for (int m4 = 0; m4 < 4; ++m4) {
        int ms = r * 4 + m4;
        int prow = m4 * 16 + kq * 4;           // pixel col within row
        #pragma unroll
        for (int rg = 0; rg < 4; ++rg)
          ep[(prow + rg) * 17 + mrow] = acc[ms][ns][rg];
      }
      #pragma unroll
      for (int oo = 0; oo < 16; ++oo) {
        int o = o0 + ns * 16 + oo;             // wave-uniform
        float v = ep[lane * 17 + oo];
        v = fmaf(v, scale_bo[b * COUT + o], nz + bias[o]);
        v = v > 0.f ? v : 0.2f * v;
        out[(((size_t)b * COUT + o) * H_ + h) * W_ + lane] = v;
      }
    }
  }
}

// =================== fallback fp32 direct conv (round-1, verified) ================
__global__ __launch_bounds__(256) void style_kernel(
    const float* __restrict__ w, const float* __restrict__ style_w,
    const float* __restrict__ style_b, float* __restrict__ style) {
  int gw = blockIdx.x * 4 + (threadIdx.x >> 6);
  int lane = threadIdx.x & 63;
  int b = gw >> 9, c = gw & 511;
  const float* wp = w + b * DLAT;
  const float* sw = style_w + c * DLAT;
  float v = 0.f;
  for (int d = lane; d < DLAT; d += 64) v = fmaf(wp[d], sw[d], v);
  #pragma unroll
  for (int off = 32; off > 0; off >>= 1) v += __shfl_down(v, off, 64);
  if (lane == 0) style[b * CIN + c] = fmaf(v, LIN_COEF, style_b[c]);
}
__global__ __launch_bounds__(256) void wsq_kernel(
    const float* __restrict__ conv_w, float* __restrict__ wsq) {
  int idx = blockIdx.x * 256 + threadIdx.x;
  const float* p = conv_w + (size_t)idx * 9;
  float s = 0.f;
  #pragma unroll
  for (int t = 0; t < 9; ++t) s = fmaf(p[t], p[t], s);
  wsq[idx] = s;
}
__global__ __launch_bounds__(256) void scale_kernel(
    const float* __restrict__ style, const float* __restrict__ wsq,
    float* __restrict__ scale_bo) {
  int gw = blockIdx.x * 4 + (threadIdx.x >> 6);
  int lane = threadIdx.x & 63;
  int b = gw >> 9, o = gw & 511;
  const float* st = style + b * CIN;
  const float* wq = wsq + o * CIN;
  float v = 0.f;
  for (int i = lane; i < CIN; i += 64) { float s = st[i]; v = fmaf(s * s, wq[i], v); }
  #pragma unroll
  for (int off = 32; off > 0; off >>= 1) v += __shfl_down(v, off, 64);
  if (lane == 0)
    scale_bo[b * COUT + o] = CONV_COEF * rsqrtf(fmaf(CONV_COEF * CONV_COEF, v, 1e-8f));
}
#define OTILE 32
#define HTILE 8
#define ICCH  8
#define XSTR  67
#define XROWS 10
__global__ __launch_bounds__(256) void conv_kernel(
    const float* __restrict__ x, const float* __restrict__ style,
    const float* __restrict__ conv_w, const float* __restrict__ scale_bo,
    const float* __restrict__ noise, const float* __restrict__ scale_noise,
    const float* __restrict__ bias, float* __restrict__ out) {
  __shared__ float xtile[ICCH * XROWS * XSTR];
  __shared__ float wt[OTILE * 72];
  const int tid = threadIdx.x;
  const int b = blockIdx.z, o0 = blockIdx.y * OTILE, h0 = blockIdx.x * HTILE;
  const int lane = tid & 63, oq = tid >> 6;
  const int r = lane >> 3, cg = lane & 7;
  float acc[8][8];
  #pragma unroll
  for (int a = 0; a < 8; ++a)
    #pragma unroll
    for (int c = 0; c < 8; ++c) acc[a][c] = 0.f;
  for (int ic0 = 0; ic0 < CIN; ic0 += ICCH) {
    for (int j = tid; j < ICCH * XROWS * XSTR; j += 256) {
      int i = j / (XROWS * XSTR);
      int rem = j - i * (XROWS * XSTR);
      int rr = rem / XSTR, cl = rem - rr * XSTR;
      if (cl < 66) {
        int hh = h0 - 1 + rr, wc = cl - 1;
        float v = 0.f;
        if ((unsigned)hh < 64u && (unsigned)wc < 64u)
          v = x[((size_t)(b * CIN + ic0 + i) * H_ + hh) * W_ + wc] * style[b * CIN + ic0 + i];
        xtile[j] = v;
      }
    }
    for (int j = tid; j < OTILE * 72; j += 256) {
      int oo = j / 72, q = j - oo * 72;
      wt[j] = conv_w[(size_t)(o0 + oo) * (CIN * 9) + ic0 * 9 + q];
    }
    __syncthreads();
    #pragma unroll 1
    for (int i = 0; i < ICCH; ++i) {
      const float* xbi = &xtile[i * (XROWS * XSTR) + r * XSTR + cg * 8];
      const float* wbi = &wt[oq * 8 * 72 + i * 9];
      #pragma unroll
      for (int ky = 0; ky < 3; ++ky) {
        float xr[10];
        #pragma unroll
        for (int q = 0; q < 10; ++q) xr[q] = xbi[ky * XSTR + q];
        #pragma unroll
        for (int kx = 0; kx < 3; ++kx) {
          #pragma unroll
          for (int oo = 0; oo < 8; ++oo) {
            float wv = wbi[oo * 72 + ky * 3 + kx];
            #pragma unroll
            for (int c = 0; c < 8; ++c) acc[oo][c] = fmaf(xr[c + kx], wv, acc[oo][c]);
          }
        }
      }
    }
    __syncthreads();
  }
  const float sn = scale_noise[0];
  const int row = h0 + r;
  float nz[8];
  #pragma unroll
  for (int c = 0; c < 8; ++c)
    nz[c] = sn * noise[((size_t)b * H_ + row) * W_ + cg * 8 + c];
  #pragma unroll
  for (int oo = 0; oo < 8; ++oo) {
    int o = o0 + oq * 8 + oo;
    float s = scale_bo[b * COUT + o];
    float bv = bias[o];
    float* op = out + ((size_t)(b * COUT + o) * H_ + row) * W_ + cg * 8;
    #pragma unroll
    for (int c = 0; c < 8; ++c) {
      float v = fmaf(acc[oo][c], s, nz[c] + bv);
      op[c] = v > 0.f ? v : 0.2f * v;
    }
  }
}

// ================================ launch ==========================================
extern "C" void kernel_launch(void* const* d_in, const int* in_sizes, int n_in,
                              void* d_out, int out_size, void* d_ws, size_t ws_size,
                              hipStream_t stream) {
  const float* x           = (const float*)d_in[0];
  const float* w           = (const float*)d_in[1];
  const float* noise       = (const float*)d_in[2];
  const float* style_w     = (const float*)d_in[3];
  const float* style_b     = (const float*)d_in[4];
  const float* conv_w      = (const float*)d_in[5];
  const float* scale_noise = (const float*)d_in[6];
  const float* bias        = (const float*)d_in[7];
  float* out = (float*)d_out;

  float* wsf      = (float*)d_ws;
  float* style    = wsf;            // 8192 f
  float* scale_bo = wsf + 8192;     // 8192 f
  float* wsq      = wsf + 16384;    // 262144 f -> ends at byte 1114112
  const size_t WTP_OFF = 1114112;
  const size_t XT_OFF  = WTP_OFF + (size_t)COUT * 9 * CIN * 2;      // +4718592
  const size_t NEED    = XT_OFF + (size_t)B_ * 66 * 66 * CIN * 2;   // 77201408

  if (ws_size >= NEED) {
    __hip_bfloat16* wtp2 = (__hip_bfloat16*)((char*)d_ws + WTP_OFF);
    __hip_bfloat16* xtp  = (__hip_bfloat16*)((char*)d_ws + XT_OFF);
    pre1<<<3072, 256, 0, stream>>>(w, style_w, style_b, conv_w, style, wsq);
    pre2<<<10816, 256, 0, stream>>>(x, style, wsq, conv_w, scale_bo, wtp2, xtp);
    dim3 grid(128, 8, 1);
    conv_mfma<<<grid, 256, 0, stream>>>(xtp, wtp2, scale_bo, noise,
                                        scale_noise, bias, out);
  } else {
    style_kernel<<<2048, 256, 0, stream>>>(w, style_w, style_b, style);
    wsq_kernel<<<1024, 256, 0, stream>>>(conv_w, wsq);
    scale_kernel<<<2048, 256, 0, stream>>>(style, wsq, scale_bo);
    dim3 grid(H_ / HTILE, COUT / OTILE, B_);
    conv_kernel<<<grid, 256, 0, stream>>>(x, style, conv_w, scale_bo,
                                          noise, scale_noise, bias, out);
  }
}